// Round 12
// baseline (25.363 us; speedup 1.0000x reference)
//
#include <hip/hip_runtime.h>

// MTGP covariance, round 12: R7 structure + all-dwordx4 stores via dead-LDS
// transpose (store-queue-entry experiment).
// cov[i,j] = sum_z W[ti,z]W[tj,z]*th[z,0]*exp(-0.5*th[z,1]*||Xi-Xj||^2) + 0.002*I
// M=4096, D=64, Z=4, fp32 in/out. Single fused kernel.
// 2080 upper-tri 64x64 tiles, 4 waves (2x2 grid of 32x32):
//  - stage fp32 X -> in-register bf16 hi/lo split -> swizzled LDS (32KB, 5 blk/CU)
//  - K-loop: 16 ds_read_b128 frags + 24 mfma 16x16x32 bf16 (hh+hl+lh)
//  - norms -> dead B-panel LDS; fused RBF epilogue
//  - NEW: direct tile routed through per-wave LDS transpose (pad-33) so ALL
//    global stores are dwordx4: 8 store instrs/wave (was 20), 128B chunks.
// Exact-once coverage (direct upper, mirror strictly-lower), deterministic.

#define M_PTS 4096
#define DIM 64
#define JITTER_F 0.002f
#define NEG_HALF_LOG2E (-0.72134752044448170f)  // -0.5*log2(e)
#define NBLK 2080                                // 64*65/2

typedef __attribute__((ext_vector_type(8))) short short8v;   // 8 bf16
typedef __attribute__((ext_vector_type(4))) float f32x4;

union FragU { short8v v; uint4 u; };

__device__ __forceinline__ float fast_exp2(float x) {
#if defined(__has_builtin)
#if __has_builtin(__builtin_amdgcn_exp2f)
  return __builtin_amdgcn_exp2f(x);
#else
  return exp2f(x);
#endif
#else
  return exp2f(x);
#endif
}

__device__ __forceinline__ unsigned bfr(float x) {  // fp32 -> bf16 (rne), as u16
  unsigned u = __float_as_uint(x);
  return (u + 0x7FFFu + ((u >> 16) & 1u)) >> 16;
}
__device__ __forceinline__ float bff(unsigned h) {  // bf16 bits -> fp32
  return __uint_as_float(h << 16);
}

__global__ __launch_bounds__(256, 5) void mtgp_fused(
    const float* __restrict__ X,      // [4096,64]
    const float* __restrict__ W,      // [4,4]
    const float* __restrict__ theta,  // [4,2]
    float* __restrict__ out) {        // [4096,4096]
  // 32KB flat LDS; panels carved manually so dead regions can be reused.
  __shared__ __align__(16) char ldsb[32768];
  unsigned short* const Ahi = (unsigned short*)(ldsb);            // 8KB
  unsigned short* const Alo = (unsigned short*)(ldsb + 8192);     // 8KB
  unsigned short* const Bhi = (unsigned short*)(ldsb + 16384);    // 8KB
  unsigned short* const Blo = (unsigned short*)(ldsb + 24576);    // 8KB

  // ---- decode item -> (u, v), v >= u, 64 slabs; prefix(u) = u*(129-u)/2 ----
  const int item = blockIdx.x;
  int u = (int)(64.5f - sqrtf(4160.25f - 2.0f * (float)item));
  if (u < 0) u = 0;
  if (u > 63) u = 63;
  while (u > 0 && u * (129 - u) / 2 > item) --u;
  while (u < 63 && (u + 1) * (128 - u) / 2 <= item) ++u;
  const int v = u + (item - u * (129 - u) / 2);
  const int grow0 = u << 6, gj0 = v << 6;

  const int tid = threadIdx.x;

  // ---- fused staging: fp32 -> hi/lo split -> k-permuted swizzled LDS ----
  // thread t: panel = (t<128 ? A : B), row = (t&127)>>1, half = t&1 (32 floats)
  const int half = tid & 1;
  const int srow = (tid & 127) >> 1;
  const bool isB = (tid >= 128);
  const int gsrow = (isB ? gj0 : grow0) + srow;
  const float4* xr = (const float4*)(X + (size_t)gsrow * DIM + half * 32);
  unsigned short* Ph = isB ? Bhi : Ahi;
  unsigned short* Pl = isB ? Blo : Alo;
  float s = 0.0f;  // row-half norm partial (fixed order -> deterministic)
#pragma unroll
  for (int kgs = 0; kgs < 4; ++kgs) {
    const float4 v0 = xr[kgs];        // locals 4k..4k+3
    const float4 v1 = xr[kgs + 4];    // locals 16+4k..16+4k+3
    s = fmaf(v0.x, v0.x, s); s = fmaf(v0.y, v0.y, s);
    s = fmaf(v0.z, v0.z, s); s = fmaf(v0.w, v0.w, s);
    s = fmaf(v1.x, v1.x, s); s = fmaf(v1.y, v1.y, s);
    s = fmaf(v1.z, v1.z, s); s = fmaf(v1.w, v1.w, s);
    const unsigned h0 = bfr(v0.x), h1 = bfr(v0.y), h2 = bfr(v0.z), h3 = bfr(v0.w);
    const unsigned h4 = bfr(v1.x), h5 = bfr(v1.y), h6 = bfr(v1.z), h7 = bfr(v1.w);
    uint4 hv = make_uint4(h0 | (h1 << 16), h2 | (h3 << 16),
                          h4 | (h5 << 16), h6 | (h7 << 16));
    const unsigned l0 = bfr(v0.x - bff(h0)), l1 = bfr(v0.y - bff(h1));
    const unsigned l2 = bfr(v0.z - bff(h2)), l3 = bfr(v0.w - bff(h3));
    const unsigned l4 = bfr(v1.x - bff(h4)), l5 = bfr(v1.y - bff(h5));
    const unsigned l6 = bfr(v1.z - bff(h6)), l7 = bfr(v1.w - bff(h7));
    uint4 lv = make_uint4(l0 | (l1 << 16), l2 | (l3 << 16),
                          l4 | (l5 << 16), l6 | (l7 << 16));
    const int f = (half << 2) + kgs;
    const int lofs = srow * 64 + ((f ^ (srow & 7)) << 3);
    *(uint4*)&Ph[lofs] = hv;
    *(uint4*)&Pl[lofs] = lv;
  }
  s += __shfl_xor(s, 1);  // pair (t, t^1) = two halves of the same row
  __syncthreads();

  const int wid = tid >> 6, lane = tid & 63;
  const int wr = (wid >> 1) << 5;          // wave row offset (0/32)
  const int wc = (wid & 1) << 5;           // wave col offset (0/32)
  const int r16 = lane & 15, kg = lane >> 4, kg4 = kg << 2;

  f32x4 acc[2][2];
#pragma unroll
  for (int p = 0; p < 2; ++p) { acc[p][0] = (f32x4)0.0f; acc[p][1] = (f32x4)0.0f; }

  // frag: lane (kg,r16) reads 16B slot f0 = k0*4+kg of row rr (one b128)
#define FRAG_LD(dst, PANEL, rr) { \
    dst.u = *(const uint4*)&PANEL[(rr) * 64 + ((f0 ^ ((rr) & 7)) << 3)]; }

#pragma unroll
  for (int k0 = 0; k0 < 2; ++k0) {
    const int f0 = (k0 << 2) + kg;
    FragU ah[2], al[2], bh[2], bl[2];
#pragma unroll
    for (int p = 0; p < 2; ++p) {
      const int ra = wr + p * 16 + r16;
      const int rb = wc + p * 16 + r16;
      FRAG_LD(ah[p], Ahi, ra)
      FRAG_LD(al[p], Alo, ra)
      FRAG_LD(bh[p], Bhi, rb)
      FRAG_LD(bl[p], Blo, rb)
    }
#pragma unroll
    for (int p = 0; p < 2; ++p)
#pragma unroll
      for (int q = 0; q < 2; ++q) {
        acc[p][q] = __builtin_amdgcn_mfma_f32_16x16x32_bf16(ah[p].v, bh[q].v, acc[p][q], 0, 0, 0);
        acc[p][q] = __builtin_amdgcn_mfma_f32_16x16x32_bf16(ah[p].v, bl[q].v, acc[p][q], 0, 0, 0);
        acc[p][q] = __builtin_amdgcn_mfma_f32_16x16x32_bf16(al[p].v, bh[q].v, acc[p][q], 0, 0, 0);
      }
  }
#undef FRAG_LD

  // ---- all panels dead after this barrier ----
  __syncthreads();
  // publish row norms into dead B-panel region
  float* const nrmw = (float*)(ldsb + 16384);
  if (half == 0) nrmw[(isB ? 64 : 0) + srow] = s;
  __syncthreads();
  const float* nrm = (const float*)(ldsb + 16384);  // [0..63]=A, [64..127]=B

  // ---- epilogue ----
  const int ti = u >> 4, tj = v >> 4;      // 16 slabs of 64 rows per task
  float czv[4], ezv[4];
#pragma unroll
  for (int z = 0; z < 4; ++z) {
    czv[z] = W[ti * 4 + z] * W[tj * 4 + z] * theta[2 * z];
    ezv[z] = NEG_HALF_LOG2E * theta[2 * z + 1];
  }
  f32x4 sqr[2];
#pragma unroll
  for (int p = 0; p < 2; ++p) sqr[p] = *(const f32x4*)&nrm[wr + p * 16 + kg4];
  float sqc[2];
#pragma unroll
  for (int q = 0; q < 2; ++q) sqc[q] = nrm[64 + wc + q * 16 + r16];

#pragma unroll
  for (int p = 0; p < 2; ++p)
#pragma unroll
    for (int q = 0; q < 2; ++q)
#pragma unroll
      for (int rr = 0; rr < 4; ++rr) {
        const float d = acc[p][q][rr];
        const float sd = fmaxf(fmaf(-2.0f, d, sqr[p][rr] + sqc[q]), 0.0f);
        float val = czv[0] * fast_exp2(ezv[0] * sd);
        val = fmaf(czv[1], fast_exp2(ezv[1] * sd), val);
        val = fmaf(czv[2], fast_exp2(ezv[2] * sd), val);
        val = fmaf(czv[3], fast_exp2(ezv[3] * sd), val);
        if (u == v && wr + p * 16 + kg4 + rr == wc + q * 16 + r16) val += JITTER_F;
        acc[p][q][rr] = val;
      }

  // ---- direct store via per-wave LDS transpose: 4 dwordx4 per wave ----
  // per-wave area in dead A-region: 16 rows x 33-float pad (2112B); reused p=0,1
  float* const T = (float*)(ldsb) + wid * 528;
#pragma unroll
  for (int p = 0; p < 2; ++p) {
#pragma unroll
    for (int q = 0; q < 2; ++q)
#pragma unroll
      for (int rr = 0; rr < 4; ++rr)
        T[(kg4 + rr) * 33 + q * 16 + r16] = acc[p][q][rr];
    // wave-internal write->read dependence; compiler inserts lgkmcnt
#pragma unroll
    for (int h = 0; h < 2; ++h) {
      const int rl = (h << 3) + (lane >> 3);          // 0..15
      const int c4 = (lane & 7) << 2;                 // 0,4,..,28
      const f32x4 vrow = *(const f32x4*)&T[rl * 33 + c4];
      *(f32x4*)(out + (size_t)(grow0 + wr + p * 16 + rl) * M_PTS + gj0 + wc + c4) = vrow;
    }
  }
  // ---- mirror store (off-diagonal only): fragment-native dwordx4 ----
  if (u != v) {
#pragma unroll
    for (int q = 0; q < 2; ++q)
#pragma unroll
      for (int p = 0; p < 2; ++p) {
        f32x4* tp = (f32x4*)(out + (size_t)(gj0 + wc + q * 16 + r16) * M_PTS + grow0 + wr + p * 16 + kg4);
        *tp = acc[p][q];
      }
  }
}

extern "C" void kernel_launch(void* const* d_in, const int* in_sizes, int n_in,
                              void* d_out, int out_size, void* d_ws, size_t ws_size,
                              hipStream_t stream) {
  const float* x     = (const float*)d_in[0];   // (4,1024,64)
  const float* W     = (const float*)d_in[1];   // (4,4)
  const float* theta = (const float*)d_in[2];   // (4,2)
  float* out = (float*)d_out;                   // (4096,4096)

  mtgp_fused<<<dim3(NBLK), dim3(256), 0, stream>>>(x, W, theta, out);
}